// Round 1
// baseline (888.408 us; speedup 1.0000x reference)
//
#include <hip/hip_runtime.h>
#include <math.h>

// Problem constants
#define BB   4096
#define KK   20
#define CC   512
#define NCLS 8631

// ---------------------------------------------------------------------------
// Pooling kernel (shared by pass 1 and pass 2).
// One block per set b. Loads x[b] (20x512 f32 = 40KB) to LDS, computes
// per-row inv-norms + dot(query, xn_row) with 16-lane groups, softmax over
// K=20, then the weighted sum -> out[b] (r for pass1, feats for pass2).
// q_stride==0: query is a single [C] vector (pass 1, global q).
// q_stride==C: query is per-set new_q[b] (pass 2).
// ---------------------------------------------------------------------------
__global__ __launch_bounds__(320) void pool_kernel(
    const float* __restrict__ x,
    const float* __restrict__ qbase, size_t q_stride,
    float* __restrict__ outv)
{
    __shared__ float xs[KK][CC];   // 40 KB
    __shared__ float red[KK];      // invnorm, then weight*invnorm
    __shared__ float dots[KK];

    const int b   = blockIdx.x;
    const int tid = threadIdx.x;

    // cooperative load of the set (float4, coalesced)
    const float4* src = (const float4*)(x + (size_t)b * (KK * CC));
    float4* dst = (float4*)&xs[0][0];
    #pragma unroll
    for (int i = tid; i < KK * CC / 4; i += 320) dst[i] = src[i];

    const float* qv = qbase + (size_t)b * q_stride;
    __syncthreads();

    // 16 lanes per row: sum-of-squares and q-dot simultaneously
    const int g = tid >> 4;   // row 0..19 (320/16 == 20)
    const int l = tid & 15;
    float ss = 0.f, qd = 0.f;
    for (int c = l; c < CC; c += 16) {
        float v = xs[g][c];
        ss = fmaf(v, v, ss);
        qd = fmaf(qv[c], v, qd);
    }
    #pragma unroll
    for (int m = 8; m >= 1; m >>= 1) {
        ss += __shfl_xor(ss, m);
        qd += __shfl_xor(qd, m);
    }
    if (l == 0) {
        float inv = 1.f / fmaxf(sqrtf(ss), 1e-12f);
        red[g]  = inv;
        dots[g] = qd * inv;
    }
    __syncthreads();

    // softmax over K=20 (threads 0..19, redundant small loops)
    if (tid < KK) {
        float m = -1e30f;
        #pragma unroll
        for (int k = 0; k < KK; ++k) m = fmaxf(m, dots[k]);
        float s = 0.f;
        #pragma unroll
        for (int k = 0; k < KK; ++k) s += __expf(dots[k] - m);
        float w = __expf(dots[tid] - m) / s;
        red[tid] = w * red[tid];   // softmax weight * invnorm
    }
    __syncthreads();

    // out[c] = sum_k (w[k]*inv[k]) * x[k][c]
    float* ob = outv + (size_t)b * CC;
    for (int c = tid; c < CC; c += 320) {
        float acc = 0.f;
        #pragma unroll
        for (int k = 0; k < KK; ++k) acc = fmaf(red[k], xs[k][c], acc);
        ob[c] = acc;
    }
}

// ---------------------------------------------------------------------------
// fp32 tiled GEMM: C[m,n] = sum_k A[m,k] * Bt[n,k] + bias[n]  (optional tanh)
// A: [M,Kd] row-major. Bt: [N,Kd] row-major (i.e. B-transposed layout).
// M, Kd assumed multiples of the tile sizes; N bounds-checked.
// ---------------------------------------------------------------------------
template<int BM, int BN, int BK, int TM, int TN, bool TANH>
__global__ __launch_bounds__(256) void gemm_bt(
    const float* __restrict__ A,
    const float* __restrict__ Bt,
    const float* __restrict__ bias,
    float* __restrict__ Cmat,
    int M, int N, int Kd)
{
    constexpr int NT = (BM / TM) * (BN / TN);
    static_assert(NT == 256, "256 threads expected");
    static_assert(BM * BK == NT * 4 && BN * BK == NT * 4, "one float4 per thread per tile");

    __shared__ float As[BK][BM];
    __shared__ float Bs[BK][BN];

    const int tid = threadIdx.x;
    const int m0 = blockIdx.x * BM;
    const int n0 = blockIdx.y * BN;
    constexpr int TX = BN / TN;
    const int tx = tid % TX;
    const int ty = tid / TX;

    constexpr int KV = BK / 4;
    const int lr = tid / KV;         // row within tile
    const int lc = (tid % KV) * 4;   // k-offset within tile

    float acc[TM][TN] = {};

    for (int k0 = 0; k0 < Kd; k0 += BK) {
        // load this iteration's tiles to registers (overlaps prior compute)
        float4 av = *(const float4*)&A[(size_t)(m0 + lr) * Kd + k0 + lc];
        float4 bv = make_float4(0.f, 0.f, 0.f, 0.f);
        int nrow = n0 + lr;
        if (nrow < N) bv = *(const float4*)&Bt[(size_t)nrow * Kd + k0 + lc];

        __syncthreads();   // previous iteration's LDS reads done
        As[lc + 0][lr] = av.x; As[lc + 1][lr] = av.y;
        As[lc + 2][lr] = av.z; As[lc + 3][lr] = av.w;
        Bs[lc + 0][lr] = bv.x; Bs[lc + 1][lr] = bv.y;
        Bs[lc + 2][lr] = bv.z; Bs[lc + 3][lr] = bv.w;
        __syncthreads();

        #pragma unroll
        for (int kk = 0; kk < BK; ++kk) {
            float a[TM], bb[TN];
            #pragma unroll
            for (int u = 0; u < TM; u += 4)
                *(float4*)&a[u] = *(const float4*)&As[kk][ty * TM + u];
            #pragma unroll
            for (int u = 0; u < TN; u += 4)
                *(float4*)&bb[u] = *(const float4*)&Bs[kk][tx * TN + u];
            #pragma unroll
            for (int i = 0; i < TM; ++i)
                #pragma unroll
                for (int j = 0; j < TN; ++j)
                    acc[i][j] = fmaf(a[i], bb[j], acc[i][j]);
        }
    }

    #pragma unroll
    for (int i = 0; i < TM; ++i) {
        int m = m0 + ty * TM + i;
        #pragma unroll
        for (int j = 0; j < TN; ++j) {
            int n = n0 + tx * TN + j;
            if (n < N) {
                float v = acc[i][j] + bias[n];
                if (TANH) v = tanhf(v);
                Cmat[(size_t)m * N + n] = v;
            }
        }
    }
}

// ---------------------------------------------------------------------------
extern "C" void kernel_launch(void* const* d_in, const int* in_sizes, int n_in,
                              void* d_out, int out_size, void* d_ws, size_t ws_size,
                              hipStream_t stream)
{
    const float* x     = (const float*)d_in[0];
    // d_in[1] = lst_lens (uniform K=20, unused)
    const float* q     = (const float*)d_in[2];
    const float* W_att = (const float*)d_in[3];
    const float* b_att = (const float*)d_in[4];
    const float* W_fc  = (const float*)d_in[5];
    const float* b_fc  = (const float*)d_in[6];

    float* feats  = (float*)d_out;                    // [B, C]
    float* logits = feats + (size_t)BB * CC;          // [B, NCLS]

    // scratch inside the logits region (overwritten by the final GEMM):
    float* r_buf  = logits;                           // [B, C]
    float* nq_buf = logits + (size_t)BB * CC;         // [B, C]

    // pass 1: r = softmax(q . xn)-weighted mean of xn
    pool_kernel<<<BB, 320, 0, stream>>>(x, q, (size_t)0, r_buf);

    // new_q = tanh(r @ W_att^T + b_att)   (M=4096, N=512, K=512)
    gemm_bt<64, 64, 16, 4, 4, true><<<dim3(BB / 64, CC / 64), 256, 0, stream>>>(
        r_buf, W_att, b_att, nq_buf, BB, CC, CC);

    // pass 2: feats = softmax(new_q . xn)-weighted mean of xn
    pool_kernel<<<BB, 320, 0, stream>>>(x, nq_buf, (size_t)CC, feats);

    // logits = feats @ W_fc^T + b_fc     (M=4096, N=8631, K=512)
    gemm_bt<128, 128, 8, 8, 8, false><<<dim3(BB / 128, (NCLS + 127) / 128), 256, 0, stream>>>(
        feats, W_fc, b_fc, logits, BB, NCLS, CC);
}

// Round 2
// 654.367 us; speedup vs baseline: 1.3577x; 1.3577x over previous
//
#include <hip/hip_runtime.h>
#include <math.h>

// Problem constants
#define BB   4096
#define KK   20
#define CC   512
#define NCLS 8631
#define NPAD 8704   // 68 * 128 (classifier N padded to tile multiple)
#define KSP  1536   // 3 * CC   (split-bf16 K concatenation)

typedef __attribute__((ext_vector_type(8))) short bf16x8;
typedef __attribute__((ext_vector_type(4))) float f32x4;

// bf16 round-to-nearest-even from float, and back (bit ops; no header deps)
static __device__ __forceinline__ unsigned short f2bf(float f) {
    unsigned int u = __float_as_uint(f);
    u += 0x7FFFu + ((u >> 16) & 1u);
    return (unsigned short)(u >> 16);
}
static __device__ __forceinline__ float bf2f(unsigned short h) {
    return __uint_as_float(((unsigned int)h) << 16);
}

// ---------------------------------------------------------------------------
// Pooling kernel (pass 1 and pass 2). One block per set b.
// ---------------------------------------------------------------------------
__global__ __launch_bounds__(320) void pool_kernel(
    const float* __restrict__ x,
    const float* __restrict__ qbase, size_t q_stride,
    float* __restrict__ outv)
{
    __shared__ float xs[KK][CC];   // 40 KB
    __shared__ float red[KK];
    __shared__ float dots[KK];

    const int b   = blockIdx.x;
    const int tid = threadIdx.x;

    const float4* src = (const float4*)(x + (size_t)b * (KK * CC));
    float4* dst = (float4*)&xs[0][0];
    #pragma unroll
    for (int i = tid; i < KK * CC / 4; i += 320) dst[i] = src[i];

    const float* qv = qbase + (size_t)b * q_stride;
    __syncthreads();

    const int g = tid >> 4;   // row 0..19
    const int l = tid & 15;
    float ss = 0.f, qd = 0.f;
    for (int c = l; c < CC; c += 16) {
        float v = xs[g][c];
        ss = fmaf(v, v, ss);
        qd = fmaf(qv[c], v, qd);
    }
    #pragma unroll
    for (int m = 8; m >= 1; m >>= 1) {
        ss += __shfl_xor(ss, m);
        qd += __shfl_xor(qd, m);
    }
    if (l == 0) {
        float inv = 1.f / fmaxf(sqrtf(ss), 1e-12f);
        red[g]  = inv;
        dots[g] = qd * inv;
    }
    __syncthreads();

    if (tid < KK) {
        float m = -1e30f;
        #pragma unroll
        for (int k = 0; k < KK; ++k) m = fmaxf(m, dots[k]);
        float s = 0.f;
        #pragma unroll
        for (int k = 0; k < KK; ++k) s += __expf(dots[k] - m);
        float w = __expf(dots[tid] - m) / s;
        red[tid] = w * red[tid];
    }
    __syncthreads();

    float* ob = outv + (size_t)b * CC;
    for (int c = tid; c < CC; c += 320) {
        float acc = 0.f;
        #pragma unroll
        for (int k = 0; k < KK; ++k) acc = fmaf(red[k], xs[k][c], acc);
        ob[c] = acc;
    }
}

// ---------------------------------------------------------------------------
// fp32 tiled GEMM (kept for the small attention GEMM + fallback path)
// ---------------------------------------------------------------------------
template<int BM, int BN, int BK, int TM, int TN, bool TANH>
__global__ __launch_bounds__(256) void gemm_bt(
    const float* __restrict__ A,
    const float* __restrict__ Bt,
    const float* __restrict__ bias,
    float* __restrict__ Cmat,
    int M, int N, int Kd)
{
    constexpr int NT = (BM / TM) * (BN / TN);
    static_assert(NT == 256, "256 threads expected");
    static_assert(BM * BK == NT * 4 && BN * BK == NT * 4, "one float4 per thread per tile");

    __shared__ float As[BK][BM];
    __shared__ float Bs[BK][BN];

    const int tid = threadIdx.x;
    const int m0 = blockIdx.x * BM;
    const int n0 = blockIdx.y * BN;
    constexpr int TX = BN / TN;
    const int tx = tid % TX;
    const int ty = tid / TX;

    constexpr int KV = BK / 4;
    const int lr = tid / KV;
    const int lc = (tid % KV) * 4;

    float acc[TM][TN] = {};

    for (int k0 = 0; k0 < Kd; k0 += BK) {
        float4 av = *(const float4*)&A[(size_t)(m0 + lr) * Kd + k0 + lc];
        float4 bv = make_float4(0.f, 0.f, 0.f, 0.f);
        int nrow = n0 + lr;
        if (nrow < N) bv = *(const float4*)&Bt[(size_t)nrow * Kd + k0 + lc];

        __syncthreads();
        As[lc + 0][lr] = av.x; As[lc + 1][lr] = av.y;
        As[lc + 2][lr] = av.z; As[lc + 3][lr] = av.w;
        Bs[lc + 0][lr] = bv.x; Bs[lc + 1][lr] = bv.y;
        Bs[lc + 2][lr] = bv.z; Bs[lc + 3][lr] = bv.w;
        __syncthreads();

        #pragma unroll
        for (int kk = 0; kk < BK; ++kk) {
            float a[TM], bb[TN];
            #pragma unroll
            for (int u = 0; u < TM; u += 4)
                *(float4*)&a[u] = *(const float4*)&As[kk][ty * TM + u];
            #pragma unroll
            for (int u = 0; u < TN; u += 4)
                *(float4*)&bb[u] = *(const float4*)&Bs[kk][tx * TN + u];
            #pragma unroll
            for (int i = 0; i < TM; ++i)
                #pragma unroll
                for (int j = 0; j < TN; ++j)
                    acc[i][j] = fmaf(a[i], bb[j], acc[i][j]);
        }
    }

    #pragma unroll
    for (int i = 0; i < TM; ++i) {
        int m = m0 + ty * TM + i;
        #pragma unroll
        for (int j = 0; j < TN; ++j) {
            int n = n0 + tx * TN + j;
            if (n < N) {
                float v = acc[i][j] + bias[n];
                if (TANH) v = tanhf(v);
                Cmat[(size_t)m * N + n] = v;
            }
        }
    }
}

// ---------------------------------------------------------------------------
// Split-bf16 conversion: in [rows_in, CC] f32 -> out [rows_out, KSP] bf16
// with three CC-wide segments. Ls==0 -> hi(bf16 rne), Ls==1 -> lo(residual).
// Rows >= rows_in are zero-filled (N padding for the GEMM).
// ---------------------------------------------------------------------------
template<int L0, int L1, int L2>
__global__ __launch_bounds__(256) void conv_split(
    const float* __restrict__ in, unsigned short* __restrict__ out,
    int rows_in, int rows_out)
{
    int idx = blockIdx.x * 256 + threadIdx.x;   // one thread per (row, col/4)
    int row = idx >> 7;                         // CC/4 == 128 groups per row
    if (row >= rows_out) return;
    int c4 = (idx & 127) << 2;

    float4 v = make_float4(0.f, 0.f, 0.f, 0.f);
    if (row < rows_in) v = *(const float4*)&in[(size_t)row * CC + c4];

    unsigned short h0 = f2bf(v.x), h1 = f2bf(v.y), h2 = f2bf(v.z), h3 = f2bf(v.w);
    ushort4 hv = make_ushort4(h0, h1, h2, h3);
    ushort4 lv = make_ushort4(f2bf(v.x - bf2f(h0)), f2bf(v.y - bf2f(h1)),
                              f2bf(v.z - bf2f(h2)), f2bf(v.w - bf2f(h3)));

    unsigned short* o = out + (size_t)row * KSP + c4;
    *(ushort4*)(o)          = L0 ? lv : hv;
    *(ushort4*)(o + CC)     = L1 ? lv : hv;
    *(ushort4*)(o + 2 * CC) = L2 ? lv : hv;
}

// ---------------------------------------------------------------------------
// bf16 MFMA GEMM (m97 structure): C[m,n] = sum_k A[m,k]*B[n,k] + bias[n]
// A: [BB, KSP] bf16 row-major. B: [NPAD, KSP] bf16 row-major (zero-padded).
// 128x128 tile, 4 waves (2x2 of 64x64), 16x16x32 MFMA, BK=32,
// global_load_lds width 16, single-buffered 2-barrier loop.
// ---------------------------------------------------------------------------
__global__ __launch_bounds__(256) void gemm_mfma_bt(
    const unsigned short* __restrict__ A,
    const unsigned short* __restrict__ B,
    const float* __restrict__ bias,
    float* __restrict__ Cmat,
    int Nn)   // real N (bound + row stride of C)
{
    __shared__ unsigned short As[128][32];   // 8 KB
    __shared__ unsigned short Bs[128][32];   // 8 KB

    const int tid  = threadIdx.x;
    const int lane = tid & 63;
    const int w    = tid >> 6;
    const int m0   = blockIdx.x * 128;
    const int n0   = blockIdx.y * 128;
    const int wr   = w >> 1;
    const int wc   = w & 1;

    f32x4 acc[4][4] = {};

    const int chunk0 = w * 128;   // wave-uniform chunk base (4 waves * 128 = 512 chunks)

    for (int k0 = 0; k0 < KSP; k0 += 32) {
        __syncthreads();   // previous iteration's LDS reads complete
        #pragma unroll
        for (int j = 0; j < 2; ++j) {
            const int cbase = chunk0 + j * 64;          // wave-uniform
            const int ch    = cbase + lane;             // this lane's chunk
            const int row   = ch >> 2;                  // tile row (0..127)
            const int kcol  = (ch & 3) << 3;            // k offset (0,8,16,24)
            const unsigned short* ga = A + (size_t)(m0 + row) * KSP + k0 + kcol;
            __builtin_amdgcn_global_load_lds(
                (const __attribute__((address_space(1))) void*)ga,
                (__attribute__((address_space(3))) void*)((char*)&As[0][0] + cbase * 16),
                16, 0, 0);
            const unsigned short* gb = B + (size_t)(n0 + row) * KSP + k0 + kcol;
            __builtin_amdgcn_global_load_lds(
                (const __attribute__((address_space(1))) void*)gb,
                (__attribute__((address_space(3))) void*)((char*)&Bs[0][0] + cbase * 16),
                16, 0, 0);
        }
        __syncthreads();   // compiler drains vmcnt before barrier

        const int kk = (lane >> 4) << 3;   // k offset of this lane's fragment
        const int rl = lane & 15;
        bf16x8 af[4], bfr[4];
        #pragma unroll
        for (int i = 0; i < 4; ++i)
            af[i] = *(const bf16x8*)&As[wr * 64 + i * 16 + rl][kk];
        #pragma unroll
        for (int j = 0; j < 4; ++j)
            bfr[j] = *(const bf16x8*)&Bs[wc * 64 + j * 16 + rl][kk];

        #pragma unroll
        for (int i = 0; i < 4; ++i)
            #pragma unroll
            for (int j = 0; j < 4; ++j)
                acc[i][j] = __builtin_amdgcn_mfma_f32_16x16x32_bf16(
                    af[i], bfr[j], acc[i][j], 0, 0, 0);
    }

    // Epilogue. C/D layout: col = lane&15, row = (lane>>4)*4 + reg  (m89-verified)
    const int rowb = m0 + wr * 64 + ((lane >> 4) << 2);
    const int colb = n0 + wc * 64 + (lane & 15);
    #pragma unroll
    for (int j = 0; j < 4; ++j) {
        const int n = colb + j * 16;
        if (n < Nn) {
            const float bia = bias[n];
            #pragma unroll
            for (int i = 0; i < 4; ++i) {
                #pragma unroll
                for (int r = 0; r < 4; ++r) {
                    const int m = rowb + i * 16 + r;
                    Cmat[(size_t)m * Nn + n] = acc[i][j][r] + bia;
                }
            }
        }
    }
}

// ---------------------------------------------------------------------------
extern "C" void kernel_launch(void* const* d_in, const int* in_sizes, int n_in,
                              void* d_out, int out_size, void* d_ws, size_t ws_size,
                              hipStream_t stream)
{
    const float* x     = (const float*)d_in[0];
    // d_in[1] = lst_lens (uniform K=20, unused)
    const float* q     = (const float*)d_in[2];
    const float* W_att = (const float*)d_in[3];
    const float* b_att = (const float*)d_in[4];
    const float* W_fc  = (const float*)d_in[5];
    const float* b_fc  = (const float*)d_in[6];

    float* feats  = (float*)d_out;                    // [B, C]
    float* logits = feats + (size_t)BB * CC;          // [B, NCLS]

    // scratch inside the logits region (consumed before the final GEMM writes):
    float* r_buf  = logits;                           // [B, C]
    float* nq_buf = logits + (size_t)BB * CC;         // [B, C]

    const size_t needA = (size_t)BB * KSP * sizeof(unsigned short);     // 12.6 MB
    const size_t needB = (size_t)NPAD * KSP * sizeof(unsigned short);   // 26.7 MB
    const bool use_mfma = ws_size >= needA + needB;
    unsigned short* Abuf = (unsigned short*)d_ws;
    unsigned short* Bbuf = Abuf + (size_t)BB * KSP;

    // pass 1: r = softmax(q . xn)-weighted mean of xn
    pool_kernel<<<BB, 320, 0, stream>>>(x, q, (size_t)0, r_buf);

    // new_q = tanh(r @ W_att^T + b_att)
    gemm_bt<64, 64, 16, 4, 4, true><<<dim3(BB / 64, CC / 64), 256, 0, stream>>>(
        r_buf, W_att, b_att, nq_buf, BB, CC, CC);

    // pass 2: feats = softmax(new_q . xn)-weighted mean of xn
    pool_kernel<<<BB, 320, 0, stream>>>(x, nq_buf, (size_t)CC, feats);

    if (use_mfma) {
        // split-bf16: logits = [Ah|Al|Ah] . [Bh|Bh|Bl]^T + b_fc
        conv_split<0, 0, 1><<<(NPAD * (CC / 4)) / 256, 256, 0, stream>>>(
            W_fc, Bbuf, NCLS, NPAD);
        conv_split<0, 1, 0><<<(BB * (CC / 4)) / 256, 256, 0, stream>>>(
            feats, Abuf, BB, BB);
        gemm_mfma_bt<<<dim3(BB / 128, NPAD / 128), 256, 0, stream>>>(
            Abuf, Bbuf, b_fc, logits, NCLS);
    } else {
        gemm_bt<128, 128, 8, 8, 8, false><<<dim3(BB / 128, (NCLS + 127) / 128), 256, 0, stream>>>(
            feats, W_fc, b_fc, logits, BB, NCLS, CC);
    }
}

// Round 6
// 532.908 us; speedup vs baseline: 1.6671x; 1.2279x over previous
//
#include <hip/hip_runtime.h>
#include <math.h>

// Problem constants
#define BB   4096
#define KK   20
#define CC   512
#define NCLS 8631
#define NPAD 8704   // 34 * 256 (classifier N padded to tile multiple)
#define KSP  1536   // 3 * CC   (split-bf16 K concatenation)
#define NTK  48     // KSP / 32 K-tiles for the 256^2 kernel

typedef __attribute__((ext_vector_type(8))) short bf16x8;
typedef __attribute__((ext_vector_type(4))) float f32x4;

static __device__ __forceinline__ unsigned short f2bf(float f) {
    unsigned int u = __float_as_uint(f);
    u += 0x7FFFu + ((u >> 16) & 1u);
    return (unsigned short)(u >> 16);
}
static __device__ __forceinline__ float bf2f(unsigned short h) {
    return __uint_as_float(((unsigned int)h) << 16);
}

// ---------------------------------------------------------------------------
// Pooling kernel (pass 1 and pass 2). One block per set b.
// ---------------------------------------------------------------------------
__global__ __launch_bounds__(320) void pool_kernel(
    const float* __restrict__ x,
    const float* __restrict__ qbase, size_t q_stride,
    float* __restrict__ outv)
{
    __shared__ float xs[KK][CC];   // 40 KB
    __shared__ float red[KK];
    __shared__ float dots[KK];

    const int b   = blockIdx.x;
    const int tid = threadIdx.x;

    const float4* src = (const float4*)(x + (size_t)b * (KK * CC));
    float4* dst = (float4*)&xs[0][0];
    for (int i = tid; i < KK * CC / 4; i += 320) dst[i] = src[i];

    const float* qv = qbase + (size_t)b * q_stride;
    __syncthreads();

    const int g = tid >> 4;   // row 0..19
    const int l = tid & 15;
    float ss = 0.f, qd = 0.f;
    #pragma unroll
    for (int c = 0; c < CC; c += 64) {
        float4 v  = *(const float4*)&xs[g][c + l * 4];
        float4 q4 = *(const float4*)&qv[c + l * 4];
        ss = fmaf(v.x, v.x, ss); ss = fmaf(v.y, v.y, ss);
        ss = fmaf(v.z, v.z, ss); ss = fmaf(v.w, v.w, ss);
        qd = fmaf(q4.x, v.x, qd); qd = fmaf(q4.y, v.y, qd);
        qd = fmaf(q4.z, v.z, qd); qd = fmaf(q4.w, v.w, qd);
    }
    #pragma unroll
    for (int m = 8; m >= 1; m >>= 1) {
        ss += __shfl_xor(ss, m);
        qd += __shfl_xor(qd, m);
    }
    if (l == 0) {
        float inv = 1.f / fmaxf(sqrtf(ss), 1e-12f);
        red[g]  = inv;
        dots[g] = qd * inv;
    }
    __syncthreads();

    if (tid < KK) {
        float m = -1e30f;
        #pragma unroll
        for (int k = 0; k < KK; ++k) m = fmaxf(m, dots[k]);
        float s = 0.f;
        #pragma unroll
        for (int k = 0; k < KK; ++k) s += __expf(dots[k] - m);
        float w = __expf(dots[tid] - m) / s;
        red[tid] = w * red[tid];
    }
    __syncthreads();

    float* ob = outv + (size_t)b * CC;
    for (int c = tid * 4; c < CC; c += 1280) {
        float4 a = make_float4(0.f, 0.f, 0.f, 0.f);
        #pragma unroll
        for (int k = 0; k < KK; ++k) {
            float w = red[k];
            float4 v = *(const float4*)&xs[k][c];
            a.x = fmaf(w, v.x, a.x); a.y = fmaf(w, v.y, a.y);
            a.z = fmaf(w, v.z, a.z); a.w = fmaf(w, v.w, a.w);
        }
        *(float4*)&ob[c] = a;
    }
}

// ---------------------------------------------------------------------------
// fp32 tiled GEMM (fallback path only)
// ---------------------------------------------------------------------------
template<int BM, int BN, int BK, int TM, int TN, bool TANH>
__global__ __launch_bounds__(256) void gemm_bt(
    const float* __restrict__ A,
    const float* __restrict__ Bt,
    const float* __restrict__ bias,
    float* __restrict__ Cmat,
    int M, int N, int Kd)
{
    constexpr int NT = (BM / TM) * (BN / TN);
    static_assert(NT == 256, "256 threads expected");
    __shared__ float As[BK][BM];
    __shared__ float Bs[BK][BN];

    const int tid = threadIdx.x;
    const int m0 = blockIdx.x * BM;
    const int n0 = blockIdx.y * BN;
    constexpr int TX = BN / TN;
    const int tx = tid % TX;
    const int ty = tid / TX;
    constexpr int KV = BK / 4;
    const int lr = tid / KV;
    const int lc = (tid % KV) * 4;

    float acc[TM][TN] = {};

    for (int k0 = 0; k0 < Kd; k0 += BK) {
        float4 av = *(const float4*)&A[(size_t)(m0 + lr) * Kd + k0 + lc];
        float4 bv = make_float4(0.f, 0.f, 0.f, 0.f);
        int nrow = n0 + lr;
        if (nrow < N) bv = *(const float4*)&Bt[(size_t)nrow * Kd + k0 + lc];
        __syncthreads();
        As[lc + 0][lr] = av.x; As[lc + 1][lr] = av.y;
        As[lc + 2][lr] = av.z; As[lc + 3][lr] = av.w;
        Bs[lc + 0][lr] = bv.x; Bs[lc + 1][lr] = bv.y;
        Bs[lc + 2][lr] = bv.z; Bs[lc + 3][lr] = bv.w;
        __syncthreads();
        #pragma unroll
        for (int kk = 0; kk < BK; ++kk) {
            float a[TM], bb[TN];
            #pragma unroll
            for (int u = 0; u < TM; u += 4)
                *(float4*)&a[u] = *(const float4*)&As[kk][ty * TM + u];
            #pragma unroll
            for (int u = 0; u < TN; u += 4)
                *(float4*)&bb[u] = *(const float4*)&Bs[kk][tx * TN + u];
            #pragma unroll
            for (int i = 0; i < TM; ++i)
                #pragma unroll
                for (int j = 0; j < TN; ++j)
                    acc[i][j] = fmaf(a[i], bb[j], acc[i][j]);
        }
    }
    #pragma unroll
    for (int i = 0; i < TM; ++i) {
        int m = m0 + ty * TM + i;
        #pragma unroll
        for (int j = 0; j < TN; ++j) {
            int n = n0 + tx * TN + j;
            if (n < N) {
                float v = acc[i][j] + bias[n];
                if (TANH) v = tanhf(v);
                Cmat[(size_t)m * N + n] = v;
            }
        }
    }
}

// ---------------------------------------------------------------------------
// Split-bf16 conversion: in [rows_in, CC] f32 -> out [rows_out, KSP] bf16
// segments [hi|hi|lo]-style per L flags; rows >= rows_in zero-filled.
// ---------------------------------------------------------------------------
template<int L0, int L1, int L2>
__global__ __launch_bounds__(256) void conv_split(
    const float* __restrict__ in, unsigned short* __restrict__ out,
    int rows_in, int rows_out)
{
    int idx = blockIdx.x * 256 + threadIdx.x;
    int row = idx >> 7;
    if (row >= rows_out) return;
    int c4 = (idx & 127) << 2;

    float4 v = make_float4(0.f, 0.f, 0.f, 0.f);
    if (row < rows_in) v = *(const float4*)&in[(size_t)row * CC + c4];

    unsigned short h0 = f2bf(v.x), h1 = f2bf(v.y), h2 = f2bf(v.z), h3 = f2bf(v.w);
    ushort4 hv = make_ushort4(h0, h1, h2, h3);
    ushort4 lv = make_ushort4(f2bf(v.x - bf2f(h0)), f2bf(v.y - bf2f(h1)),
                              f2bf(v.z - bf2f(h2)), f2bf(v.w - bf2f(h3)));

    unsigned short* o = out + (size_t)row * KSP + c4;
    *(ushort4*)(o)          = L0 ? lv : hv;
    *(ushort4*)(o + CC)     = L1 ? lv : hv;
    *(ushort4*)(o + 2 * CC) = L2 ? lv : hv;
}

// ---------------------------------------------------------------------------
// 128^2 bf16 MFMA GEMM (m97 structure, verified round 2) — attention pass
// and mid-size fallback. Optional tanh epilogue.
// ---------------------------------------------------------------------------
template<bool TANH>
__global__ __launch_bounds__(256) void gemm_mfma_bt(
    const unsigned short* __restrict__ A,
    const unsigned short* __restrict__ B,
    const float* __restrict__ bias,
    float* __restrict__ Cmat,
    int Nn)
{
    __shared__ unsigned short As[128][32];
    __shared__ unsigned short Bs[128][32];

    const int tid  = threadIdx.x;
    const int lane = tid & 63;
    const int w    = tid >> 6;
    const int m0   = blockIdx.x * 128;
    const int n0   = blockIdx.y * 128;
    const int wr   = w >> 1;
    const int wc   = w & 1;

    f32x4 acc[4][4] = {};
    const int chunk0 = w * 128;

    for (int k0 = 0; k0 < KSP; k0 += 32) {
        __syncthreads();
        #pragma unroll
        for (int j = 0; j < 2; ++j) {
            const int cbase = chunk0 + j * 64;
            const int ch    = cbase + lane;
            const int row   = ch >> 2;
            const int kcol  = (ch & 3) << 3;
            const unsigned short* ga = A + (size_t)(m0 + row) * KSP + k0 + kcol;
            __builtin_amdgcn_global_load_lds(
                (const __attribute__((address_space(1))) void*)ga,
                (__attribute__((address_space(3))) void*)((char*)&As[0][0] + cbase * 16),
                16, 0, 0);
            const unsigned short* gb = B + (size_t)(n0 + row) * KSP + k0 + kcol;
            __builtin_amdgcn_global_load_lds(
                (const __attribute__((address_space(1))) void*)gb,
                (__attribute__((address_space(3))) void*)((char*)&Bs[0][0] + cbase * 16),
                16, 0, 0);
        }
        __syncthreads();

        const int kk = (lane >> 4) << 3;
        const int rl = lane & 15;
        bf16x8 af[4], bfr[4];
        #pragma unroll
        for (int i = 0; i < 4; ++i)
            af[i] = *(const bf16x8*)&As[wr * 64 + i * 16 + rl][kk];
        #pragma unroll
        for (int j = 0; j < 4; ++j)
            bfr[j] = *(const bf16x8*)&Bs[wc * 64 + j * 16 + rl][kk];

        #pragma unroll
        for (int i = 0; i < 4; ++i)
            #pragma unroll
            for (int j = 0; j < 4; ++j)
                acc[i][j] = __builtin_amdgcn_mfma_f32_16x16x32_bf16(
                    af[i], bfr[j], acc[i][j], 0, 0, 0);
    }

    const int rowb = m0 + wr * 64 + ((lane >> 4) << 2);
    const int colb = n0 + wc * 64 + (lane & 15);
    #pragma unroll
    for (int j = 0; j < 4; ++j) {
        const int n = colb + j * 16;
        if (n < Nn) {
            const float bia = bias[n];
            #pragma unroll
            for (int i = 0; i < 4; ++i) {
                #pragma unroll
                for (int r = 0; r < 4; ++r) {
                    const int m = rowb + i * 16 + r;
                    float v = acc[i][j][r] + bia;
                    if (TANH) v = tanhf(v);
                    Cmat[(size_t)m * Nn + n] = v;
                }
            }
        }
    }
}

// ---------------------------------------------------------------------------
// 256^2 pipelined bf16 MFMA GEMM (classifier).
// BK=32, 4 LDS slots (A 4x16KB + B 4x16KB = 128KB), stage-ahead-3 K-tiles,
// counted s_waitcnt vmcnt(8) (never 0 in the loop), raw s_barrier, setprio
// around 16-MFMA clusters, XOR bank swizzle chunk^=((row>>1)&3) applied as
// pre-swizzled global source (linear global_load_lds dest) + swizzled read.
// 8 waves = 2(M) x 4(N); per wave 128x64 C-block (acc[8][4] f32x4).
// ---------------------------------------------------------------------------
__global__ __launch_bounds__(512, 2) void gemm_mfma256(
    const unsigned short* __restrict__ A,   // [4096][KSP]
    const unsigned short* __restrict__ B,   // [NPAD][KSP]
    const float* __restrict__ bias,
    float* __restrict__ Cmat,
    int Nn, int mblocks)
{
    __shared__ char smem[131072];   // A slots [0,64K), B slots [64K,128K)

    const int tid  = threadIdx.x;
    const int lane = tid & 63;
    const int w    = tid >> 6;
    const int wm   = w >> 2;        // 0..1
    const int wn   = w & 3;         // 0..3
    const int rl   = lane & 15;
    const int cw   = lane >> 4;     // 0..3

    // XCD-aware block swizzle (gridDim.x % 8 == 0)
    const int cpx = (int)gridDim.x >> 3;
    const int wg  = ((int)blockIdx.x & 7) * cpx + ((int)blockIdx.x >> 3);
    const int m0  = (wg % mblocks) * 256;
    const int n0  = (wg / mblocks) * 256;

    // staging: per K-tile each thread does 4 x 16B loads:
    //   j0: A chunk d=tid, j1: A chunk d=tid+512, j2/j3 same for B.
    // dest chunk d -> row=d>>2, stored logical k-chunk = (d&3)^((row>>1)&3).
    const int rowA = tid >> 2;
    const int lcs  = (tid & 3) ^ ((rowA >> 1) & 3);
    const unsigned short* pA0 = A + (size_t)(m0 + rowA) * KSP + lcs * 8;
    const unsigned short* pA1 = pA0 + (size_t)128 * KSP;
    const unsigned short* pB0 = B + (size_t)(n0 + rowA) * KSP + lcs * 8;
    const unsigned short* pB1 = pB0 + (size_t)128 * KSP;
    const int wbyte = w * 1024;

    #define STAGE_A(slot, k0s)                                                  \
        do {                                                                    \
            __builtin_amdgcn_global_load_lds(                                   \
                (const __attribute__((address_space(1))) void*)(pA0 + (k0s)),   \
                (__attribute__((address_space(3))) void*)(smem + (slot) * 16384 + wbyte), \
                16, 0, 0);                                                      \
            __builtin_amdgcn_global_load_lds(                                   \
                (const __attribute__((address_space(1))) void*)(pA1 + (k0s)),   \
                (__attribute__((address_space(3))) void*)(smem + (slot) * 16384 + 8192 + wbyte), \
                16, 0, 0);                                                      \
        } while (0)
    #define STAGE_B(slot, k0s)                                                  \
        do {                                                                    \
            __builtin_amdgcn_global_load_lds(                                   \
                (const __attribute__((address_space(1))) void*)(pB0 + (k0s)),   \
                (__attribute__((address_space(3))) void*)(smem + 65536 + (slot) * 16384 + wbyte), \
                16, 0, 0);                                                      \
            __builtin_amdgcn_global_load_lds(                                   \
                (const __attribute__((address_space(1))) void*)(pB1 + (k0s)),   \
                (__attribute__((address_space(3))) void*)(smem + 65536 + (slot) * 16384 + 8192 + wbyte), \
                16, 0, 0);                                                      \
        } while (0)

    // lane-local byte offset within a slot for ds_read (swizzled):
    // row=rl (+frag*16), chunk' = cw ^ ((rl>>1)&3)
    const int albase = rl * 64 + ((cw ^ ((rl >> 1) & 3)) << 4);

    f32x4 acc[8][4] = {};

    // prologue: stage K-tiles 0,1,2 (slots 0,1,2)
    #pragma unroll
    for (int pt = 0; pt < 3; ++pt) {
        STAGE_A(pt, pt * 32);
        STAGE_B(pt, pt * 32);
    }
    asm volatile("s_waitcnt vmcnt(8)" ::: "memory");   // K-tile 0 landed
    __builtin_amdgcn_s_barrier();

    for (int t = 0; t < NTK; ++t) {
        const int slot = t & 3;
        const int ts   = t + 3;
        const int k0s  = (ts < NTK) ? ts * 32 : 0;   // clamp: tail stages re-read kt0 (never consumed)
        const int sst  = ts & 3;
        const char* sa = smem + slot * 16384 + wm * 8192 + albase;
        const char* sb = smem + 65536 + slot * 16384 + wn * 4096 + albase;

        bf16x8 af[4], bf[4];
        // ---- phase A: m-frags 0..3, all 4 n-frags ----
        #pragma unroll
        for (int i = 0; i < 4; ++i) af[i] = *(const bf16x8*)(sa + i * 1024);
        #pragma unroll
        for (int n = 0; n < 4; ++n) bf[n] = *(const bf16x8*)(sb + n * 1024);
        STAGE_A(sst, k0s);
        __builtin_amdgcn_s_barrier();
        asm volatile("s_waitcnt lgkmcnt(0)" ::: "memory");
        __builtin_amdgcn_s_setprio(1);
        #pragma unroll
        for (int i = 0; i < 4; ++i)
            #pragma unroll
            for (int n = 0; n < 4; ++n)
                acc[i][n] = __builtin_amdgcn_mfma_f32_16x16x32_bf16(
                    af[i], bf[n], acc[i][n], 0, 0, 0);
        __builtin_amdgcn_s_setprio(0);
        __builtin_amdgcn_s_barrier();

        // ---- phase B: m-frags 4..7 (reuse bf) ----
        #pragma unroll
        for (int i = 0; i < 4; ++i) af[i] = *(const bf16x8*)(sa + 4096 + i * 1024);
        STAGE_B(sst, k0s);
        __builtin_amdgcn_s_barrier();
        asm volatile("s_waitcnt lgkmcnt(0)" ::: "memory");
        __builtin_amdgcn_s_setprio(1);
        #pragma unroll
        for (int i = 0; i < 4; ++i)
            #pragma unroll
            for (int n = 0; n < 4; ++n)
                acc[4 + i][n] = __builtin_amdgcn_mfma_f32_16x16x32_bf16(
                    af[i], bf[n], acc[4 + i][n], 0, 0, 0);
        __builtin_amdgcn_s_setprio(0);
        // counted wait: outstanding = {t+1:4, t+2:4, t+3:4}; drain oldest 4.
        asm volatile("s_waitcnt vmcnt(8)" ::: "memory");
        __builtin_amdgcn_s_barrier();
    }
    asm volatile("s_waitcnt vmcnt(0)" ::: "memory");   // tail stages before endpgm

    // epilogue: C[m][n], frag layout col=lane&15, row=(lane>>4)*4+reg
    const int mwb = m0 + wm * 128 + (cw << 2);
    const int nwb = n0 + wn * 64 + rl;
    #pragma unroll
    for (int mf = 0; mf < 8; ++mf) {
        #pragma unroll
        for (int n = 0; n < 4; ++n) {
            const int ncol = nwb + n * 16;
            if (ncol < Nn) {
                const float bia = bias[ncol];
                float* cp = Cmat + (size_t)(mwb + mf * 16) * Nn + ncol;
                #pragma unroll
                for (int r = 0; r < 4; ++r)
                    cp[(size_t)r * Nn] = acc[mf][n][r] + bia;
            }
        }
    }
    #undef STAGE_A
    #undef STAGE_B
}

// ---------------------------------------------------------------------------
extern "C" void kernel_launch(void* const* d_in, const int* in_sizes, int n_in,
                              void* d_out, int out_size, void* d_ws, size_t ws_size,
                              hipStream_t stream)
{
    const float* x     = (const float*)d_in[0];
    // d_in[1] = lst_lens (uniform K=20, unused)
    const float* q     = (const float*)d_in[2];
    const float* W_att = (const float*)d_in[3];
    const float* b_att = (const float*)d_in[4];
    const float* W_fc  = (const float*)d_in[5];
    const float* b_fc  = (const float*)d_in[6];

    float* feats  = (float*)d_out;                    // [B, C]
    float* logits = feats + (size_t)BB * CC;          // [B, NCLS]

    float* r_buf  = logits;                           // [B, C] scratch
    float* nq_buf = logits + (size_t)BB * CC;         // [B, C] scratch

    const size_t need_cls = (size_t)(BB + NPAD) * KSP * 2;            // 39.3 MB
    const size_t need_all = need_cls + (size_t)(BB + CC) * KSP * 2;   // 53.5 MB
    const bool mfma_cls = ws_size >= need_cls;
    const bool mfma_att = ws_size >= need_all;

    unsigned short* Abuf = (unsigned short*)d_ws;          // feats split [BB]
    unsigned short* Bbuf = Abuf + (size_t)BB * KSP;        // W_fc split  [NPAD]
    unsigned short* Arb  = Bbuf + (size_t)NPAD * KSP;      // r split     [BB]
    unsigned short* Wab  = Arb  + (size_t)BB * KSP;        // W_att split [CC]

    // independent weight conversions first
    if (mfma_cls)
        conv_split<0, 0, 1><<<(NPAD * (CC / 4)) / 256, 256, 0, stream>>>(
            W_fc, Bbuf, NCLS, NPAD);
    if (mfma_att)
        conv_split<0, 0, 1><<<(CC * (CC / 4)) / 256, 256, 0, stream>>>(
            W_att, Wab, CC, CC);

    // pass 1: r = softmax(q . xn)-weighted mean of xn
    pool_kernel<<<BB, 320, 0, stream>>>(x, q, (size_t)0, r_buf);

    // new_q = tanh(r @ W_att^T + b_att)
    if (mfma_att) {
        conv_split<0, 1, 0><<<(BB * (CC / 4)) / 256, 256, 0, stream>>>(
            r_buf, Arb, BB, BB);
        gemm_mfma_bt<true><<<dim3(BB / 128, CC / 128), 256, 0, stream>>>(
            Arb, Wab, b_att, nq_buf, CC);
    } else {
        gemm_bt<64, 64, 16, 4, 4, true><<<dim3(BB / 64, CC / 64), 256, 0, stream>>>(
            r_buf, W_att, b_att, nq_buf, BB, CC, CC);
    }

    // pass 2: feats = softmax(new_q . xn)-weighted mean of xn
    pool_kernel<<<BB, 320, 0, stream>>>(x, nq_buf, (size_t)CC, feats);

    // logits = feats @ W_fc^T + b_fc
    if (mfma_cls) {
        conv_split<0, 1, 0><<<(BB * (CC / 4)) / 256, 256, 0, stream>>>(
            feats, Abuf, BB, BB);
        gemm_mfma256<<<dim3((BB / 256) * (NPAD / 256)), 512, 0, stream>>>(
            Abuf, Bbuf, b_fc, logits, NCLS, BB / 256);
    } else {
        gemm_bt<128, 128, 8, 8, 8, false><<<dim3(BB / 128, (NCLS + 127) / 128), 256, 0, stream>>>(
            feats, W_fc, b_fc, logits, BB, NCLS, CC);
    }
}

// Round 9
// 530.927 us; speedup vs baseline: 1.6733x; 1.0037x over previous
//
#include <hip/hip_runtime.h>
#include <math.h>

// Problem constants
#define BB   4096
#define KK   20
#define CC   512
#define NCLS 8631
#define KSP  1536   // 3 * CC (split-bf16 K concatenation)
#define NTK  48     // KSP / 32 K-tiles

// classifier tile geometry: 128 x 384, 736 blocks (rounds 256/256/224)
#define BMC  128
#define BNC  384
#define NPAD 8832   // 23 * 384
#define MBLK (BB / BMC)     // 32
#define NBLK (NPAD / BNC)   // 23

typedef __attribute__((ext_vector_type(8))) short bf16x8;
typedef __attribute__((ext_vector_type(4))) float f32x4;

static __device__ __forceinline__ unsigned short f2bf(float f) {
    unsigned int u = __float_as_uint(f);
    u += 0x7FFFu + ((u >> 16) & 1u);
    return (unsigned short)(u >> 16);
}
static __device__ __forceinline__ float bf2f(unsigned short h) {
    return __uint_as_float(((unsigned int)h) << 16);
}

// ---------------------------------------------------------------------------
// Pooling kernel. One block per set b. Optionally writes f32 row (outf) and/or
// split-bf16 [hi|lo|hi] row of width KSP (outs) -- fused conv_split<0,1,0>.
// ---------------------------------------------------------------------------
template<int WF32, int WSPL>
__global__ __launch_bounds__(320) void pool_kernel(
    const float* __restrict__ x,
    const float* __restrict__ qbase, size_t q_stride,
    float* __restrict__ outf, unsigned short* __restrict__ outs)
{
    __shared__ float xs[KK][CC];   // 40 KB
    __shared__ float red[KK];
    __shared__ float dots[KK];

    const int b   = blockIdx.x;
    const int tid = threadIdx.x;

    const float4* src = (const float4*)(x + (size_t)b * (KK * CC));
    float4* dst = (float4*)&xs[0][0];
    for (int i = tid; i < KK * CC / 4; i += 320) dst[i] = src[i];

    const float* qv = qbase + (size_t)b * q_stride;
    __syncthreads();

    const int g = tid >> 4;   // row 0..19
    const int l = tid & 15;
    float ss = 0.f, qd = 0.f;
    #pragma unroll
    for (int c = 0; c < CC; c += 64) {
        float4 v  = *(const float4*)&xs[g][c + l * 4];
        float4 q4 = *(const float4*)&qv[c + l * 4];
        ss = fmaf(v.x, v.x, ss); ss = fmaf(v.y, v.y, ss);
        ss = fmaf(v.z, v.z, ss); ss = fmaf(v.w, v.w, ss);
        qd = fmaf(q4.x, v.x, qd); qd = fmaf(q4.y, v.y, qd);
        qd = fmaf(q4.z, v.z, qd); qd = fmaf(q4.w, v.w, qd);
    }
    #pragma unroll
    for (int m = 8; m >= 1; m >>= 1) {
        ss += __shfl_xor(ss, m);
        qd += __shfl_xor(qd, m);
    }
    if (l == 0) {
        float inv = 1.f / fmaxf(sqrtf(ss), 1e-12f);
        red[g]  = inv;
        dots[g] = qd * inv;
    }
    __syncthreads();

    if (tid < KK) {
        float m = -1e30f;
        #pragma unroll
        for (int k = 0; k < KK; ++k) m = fmaxf(m, dots[k]);
        float s = 0.f;
        #pragma unroll
        for (int k = 0; k < KK; ++k) s += __expf(dots[k] - m);
        float w = __expf(dots[tid] - m) / s;
        red[tid] = w * red[tid];
    }
    __syncthreads();

    for (int c = tid * 4; c < CC; c += 1280) {
        float4 a = make_float4(0.f, 0.f, 0.f, 0.f);
        #pragma unroll
        for (int k = 0; k < KK; ++k) {
            float w = red[k];
            float4 v = *(const float4*)&xs[k][c];
            a.x = fmaf(w, v.x, a.x); a.y = fmaf(w, v.y, a.y);
            a.z = fmaf(w, v.z, a.z); a.w = fmaf(w, v.w, a.w);
        }
        if (WF32) *(float4*)&outf[(size_t)b * CC + c] = a;
        if (WSPL) {
            unsigned short h0 = f2bf(a.x), h1 = f2bf(a.y),
                           h2 = f2bf(a.z), h3 = f2bf(a.w);
            ushort4 hv = make_ushort4(h0, h1, h2, h3);
            ushort4 lv = make_ushort4(f2bf(a.x - bf2f(h0)), f2bf(a.y - bf2f(h1)),
                                      f2bf(a.z - bf2f(h2)), f2bf(a.w - bf2f(h3)));
            unsigned short* o = outs + (size_t)b * KSP + c;
            *(ushort4*)(o)          = hv;   // hi
            *(ushort4*)(o + CC)     = lv;   // lo
            *(ushort4*)(o + 2 * CC) = hv;   // hi
        }
    }
}

// ---------------------------------------------------------------------------
// fp32 tiled GEMM (fallback path only)
// ---------------------------------------------------------------------------
template<int BM, int BN, int BK, int TM, int TN, bool TANH>
__global__ __launch_bounds__(256) void gemm_bt(
    const float* __restrict__ A,
    const float* __restrict__ Bt,
    const float* __restrict__ bias,
    float* __restrict__ Cmat,
    int M, int N, int Kd)
{
    constexpr int NT = (BM / TM) * (BN / TN);
    static_assert(NT == 256, "256 threads expected");
    __shared__ float As[BK][BM];
    __shared__ float Bs[BK][BN];

    const int tid = threadIdx.x;
    const int m0 = blockIdx.x * BM;
    const int n0 = blockIdx.y * BN;
    constexpr int TX = BN / TN;
    const int tx = tid % TX;
    const int ty = tid / TX;
    constexpr int KV = BK / 4;
    const int lr = tid / KV;
    const int lc = (tid % KV) * 4;

    float acc[TM][TN] = {};

    for (int k0 = 0; k0 < Kd; k0 += BK) {
        float4 av = *(const float4*)&A[(size_t)(m0 + lr) * Kd + k0 + lc];
        float4 bv = make_float4(0.f, 0.f, 0.f, 0.f);
        int nrow = n0 + lr;
        if (nrow < N) bv = *(const float4*)&Bt[(size_t)nrow * Kd + k0 + lc];
        __syncthreads();
        As[lc + 0][lr] = av.x; As[lc + 1][lr] = av.y;
        As[lc + 2][lr] = av.z; As[lc + 3][lr] = av.w;
        Bs[lc + 0][lr] = bv.x; Bs[lc + 1][lr] = bv.y;
        Bs[lc + 2][lr] = bv.z; Bs[lc + 3][lr] = bv.w;
        __syncthreads();
        #pragma unroll
        for (int kk = 0; kk < BK; ++kk) {
            float a[TM], bb[TN];
            #pragma unroll
            for (int u = 0; u < TM; u += 4)
                *(float4*)&a[u] = *(const float4*)&As[kk][ty * TM + u];
            #pragma unroll
            for (int u = 0; u < TN; u += 4)
                *(float4*)&bb[u] = *(const float4*)&Bs[kk][tx * TN + u];
            #pragma unroll
            for (int i = 0; i < TM; ++i)
                #pragma unroll
                for (int j = 0; j < TN; ++j)
                    acc[i][j] = fmaf(a[i], bb[j], acc[i][j]);
        }
    }
    #pragma unroll
    for (int i = 0; i < TM; ++i) {
        int m = m0 + ty * TM + i;
        #pragma unroll
        for (int j = 0; j < TN; ++j) {
            int n = n0 + tx * TN + j;
            if (n < N) {
                float v = acc[i][j] + bias[n];
                if (TANH) v = tanhf(v);
                Cmat[(size_t)m * N + n] = v;
            }
        }
    }
}

// ---------------------------------------------------------------------------
// Split-bf16 conversion for WEIGHTS: [rows_in, CC] f32 -> [rows_out, KSP]
// bf16 segments [hi|hi|lo]; rows >= rows_in zero-filled.
// ---------------------------------------------------------------------------
__global__ __launch_bounds__(256) void conv_split_w(
    const float* __restrict__ in, unsigned short* __restrict__ out,
    int rows_in, int rows_out)
{
    int idx = blockIdx.x * 256 + threadIdx.x;
    int row = idx >> 7;
    if (row >= rows_out) return;
    int c4 = (idx & 127) << 2;

    float4 v = make_float4(0.f, 0.f, 0.f, 0.f);
    if (row < rows_in) v = *(const float4*)&in[(size_t)row * CC + c4];

    unsigned short h0 = f2bf(v.x), h1 = f2bf(v.y), h2 = f2bf(v.z), h3 = f2bf(v.w);
    ushort4 hv = make_ushort4(h0, h1, h2, h3);
    ushort4 lv = make_ushort4(f2bf(v.x - bf2f(h0)), f2bf(v.y - bf2f(h1)),
                              f2bf(v.z - bf2f(h2)), f2bf(v.w - bf2f(h3)));

    unsigned short* o = out + (size_t)row * KSP + c4;
    *(ushort4*)(o)          = hv;
    *(ushort4*)(o + CC)     = hv;
    *(ushort4*)(o + 2 * CC) = lv;
}

// ---------------------------------------------------------------------------
// 128^2 bf16 MFMA GEMM (m97 structure, verified) — attention pass.
// ---------------------------------------------------------------------------
template<bool TANH>
__global__ __launch_bounds__(256) void gemm_mfma_bt(
    const unsigned short* __restrict__ A,
    const unsigned short* __restrict__ B,
    const float* __restrict__ bias,
    float* __restrict__ Cmat,
    int Nn)
{
    __shared__ unsigned short As[128][32];
    __shared__ unsigned short Bs[128][32];

    const int tid  = threadIdx.x;
    const int lane = tid & 63;
    const int w    = tid >> 6;
    const int m0   = blockIdx.x * 128;
    const int n0   = blockIdx.y * 128;
    const int wr   = w >> 1;
    const int wc   = w & 1;

    f32x4 acc[4][4] = {};
    const int chunk0 = w * 128;

    for (int k0 = 0; k0 < KSP; k0 += 32) {
        __syncthreads();
        #pragma unroll
        for (int j = 0; j < 2; ++j) {
            const int cbase = chunk0 + j * 64;
            const int ch    = cbase + lane;
            const int row   = ch >> 2;
            const int kcol  = (ch & 3) << 3;
            const unsigned short* ga = A + (size_t)(m0 + row) * KSP + k0 + kcol;
            __builtin_amdgcn_global_load_lds(
                (const __attribute__((address_space(1))) void*)ga,
                (__attribute__((address_space(3))) void*)((char*)&As[0][0] + cbase * 16),
                16, 0, 0);
            const unsigned short* gb = B + (size_t)(n0 + row) * KSP + k0 + kcol;
            __builtin_amdgcn_global_load_lds(
                (const __attribute__((address_space(1))) void*)gb,
                (__attribute__((address_space(3))) void*)((char*)&Bs[0][0] + cbase * 16),
                16, 0, 0);
        }
        __syncthreads();

        const int kk = (lane >> 4) << 3;
        const int rl = lane & 15;
        bf16x8 af[4], bfr[4];
        #pragma unroll
        for (int i = 0; i < 4; ++i)
            af[i] = *(const bf16x8*)&As[wr * 64 + i * 16 + rl][kk];
        #pragma unroll
        for (int j = 0; j < 4; ++j)
            bfr[j] = *(const bf16x8*)&Bs[wc * 64 + j * 16 + rl][kk];

        #pragma unroll
        for (int i = 0; i < 4; ++i)
            #pragma unroll
            for (int j = 0; j < 4; ++j)
                acc[i][j] = __builtin_amdgcn_mfma_f32_16x16x32_bf16(
                    af[i], bfr[j], acc[i][j], 0, 0, 0);
    }

    const int rowb = m0 + wr * 64 + ((lane >> 4) << 2);
    const int colb = n0 + wc * 64 + (lane & 15);
    #pragma unroll
    for (int j = 0; j < 4; ++j) {
        const int n = colb + j * 16;
        if (n < Nn) {
            const float bia = bias[n];
            #pragma unroll
            for (int i = 0; i < 4; ++i) {
                #pragma unroll
                for (int r = 0; r < 4; ++r) {
                    const int m = rowb + i * 16 + r;
                    float v = acc[i][j][r] + bia;
                    if (TANH) v = tanhf(v);
                    Cmat[(size_t)m * Nn + n] = v;
                }
            }
        }
    }
}

// ---------------------------------------------------------------------------
// Classifier GEMM: 128x384 tile, 736 blocks (rounds 256/256/224), BK=32,
// 4 LDS slots (A 4x8KB + B 4x24KB = 128KB), stage-ahead-3 + counted vmcnt(8),
// ONE barrier per K-tile (T3 minimum recipe), setprio around 24-MFMA cluster,
// XOR bank swizzle (pre-swizzled global source, swizzled ds_read).
// 8 waves = 2(M) x 4(N); per wave 64x96 (acc[4][6]).
// ---------------------------------------------------------------------------
__global__ __launch_bounds__(512, 2) void gemm_cls(
    const unsigned short* __restrict__ A,   // [BB][KSP]
    const unsigned short* __restrict__ B,   // [NPAD][KSP]
    const float* __restrict__ bias,
    float* __restrict__ Cmat,
    int Nn)
{
    __shared__ char smem[131072];   // A slots [0,32K), B slots [32K,128K)

    const int tid  = threadIdx.x;
    const int lane = tid & 63;
    const int w    = tid >> 6;
    const int wm   = w >> 2;        // 0..1
    const int wn   = w & 3;         // 0..3
    const int rl   = lane & 15;
    const int cw   = lane >> 4;     // 0..3

    // XCD-aware bijective swizzle (gridDim.x = 736 = 92*8)
    const int cpx = (int)gridDim.x >> 3;
    const int wg  = ((int)blockIdx.x & 7) * cpx + ((int)blockIdx.x >> 3);
    const int m0  = (wg % MBLK) * BMC;
    const int n0  = (wg / MBLK) * BNC;

    // staging: 4 x 16B loads per thread per K-tile: 1 A chunk (d=tid),
    // 3 B chunks (d=tid, tid+512, tid+1024). chunk d -> row=d>>2,
    // stored logical k-chunk = (d&3)^((row>>1)&3)  (row+128 invariant).
    const int rowd = tid >> 2;
    const int lcs  = (tid & 3) ^ ((rowd >> 1) & 3);
    const unsigned short* pA  = A + (size_t)(m0 + rowd) * KSP + lcs * 8;
    const unsigned short* pB0 = B + (size_t)(n0 + rowd) * KSP + lcs * 8;
    const unsigned short* pB1 = pB0 + (size_t)128 * KSP;
    const unsigned short* pB2 = pB0 + (size_t)256 * KSP;
    const int wbyte = w * 1024;

    #define STG(p, off)                                                        \
        __builtin_amdgcn_global_load_lds(                                      \
            (const __attribute__((address_space(1))) void*)(p),                \
            (__attribute__((address_space(3))) void*)(smem + (off) + wbyte),   \
            16, 0, 0)
    #define STAGE_T(slot, k0s)                                                 \
        do {                                                                   \
            STG(pA  + (k0s), (slot) * 8192);                                   \
            STG(pB0 + (k0s), 32768 + (slot) * 24576);                          \
            STG(pB1 + (k0s), 32768 + (slot) * 24576 + 8192);                   \
            STG(pB2 + (k0s), 32768 + (slot) * 24576 + 16384);                  \
        } while (0)

    // swizzled lane-local byte offset within a slot (same for all frags:
    // frag row offsets are multiples of 16, (row>>1)&3 invariant)
    const int albase = rl * 64 + ((cw ^ ((rl >> 1) & 3)) << 4);

    f32x4 acc[4][6] = {};

    // prologue: stage K-tiles 0,1,2 into slots 0,1,2 (12 loads)
    #pragma unroll
    for (int pt = 0; pt < 3; ++pt) STAGE_T(pt, pt * 32);
    asm volatile("s_waitcnt vmcnt(8)" ::: "memory");   // K-tile 0 landed
    __builtin_amdgcn_s_barrier();

    for (int t = 0; t < NTK; ++t) {
        const int slot = t & 3;
        const int ts   = t + 3;
        const int k0s  = (ts < NTK) ? ts * 32 : 0;   // tail: restage dead slots
        const int sst  = ts & 3;

        STAGE_T(sst, k0s);   // issue next-tile loads first (fly under MFMA)

        const char* sa = smem + slot * 8192 + wm * 4096 + albase;
        const char* sb = smem + 32768 + slot * 24576 + wn * 6144 + albase;
        bf16x8 af[4], bf[6];
        #pragma unroll
        for (int i = 0; i < 4; ++i) af[i] = *(const bf16x8*)(sa + i * 1024);
        #pragma unroll
        for (int n = 0; n < 6; ++n) bf[n] = *(const bf16x8*)(sb + n * 1024);

        __builtin_amdgcn_s_setprio(1);
        #pragma unroll
        for (int i = 0; i < 4; ++i)
            #pragma unroll
            for (int n = 0; n < 6; ++n)
                acc[i][n] = __builtin_amdgcn_mfma_f32_16x16x32_bf16(
                    af[i], bf[n], acc[i][n], 0, 0, 0);
        __builtin_amdgcn_s_setprio(0);

        // counted wait: 12 outstanding -> drain oldest 4 (tile t+1 landed)
        asm volatile("s_waitcnt vmcnt(8)" ::: "memory");
        __builtin_amdgcn_s_barrier();
    }
    asm volatile("s_waitcnt vmcnt(0)" ::: "memory");   // drain tail stages

    // epilogue: C/D layout col=lane&15, row=(lane>>4)*4+reg (verified)
    const int mwb = m0 + wm * 64 + (cw << 2);
    const int nwb = n0 + wn * 96 + rl;
    #pragma unroll
    for (int mf = 0; mf < 4; ++mf) {
        #pragma unroll
        for (int n = 0; n < 6; ++n) {
            const int ncol = nwb + n * 16;
            if (ncol < Nn) {
                const float bia = bias[ncol];
                float* cp = Cmat + (size_t)(mwb + mf * 16) * Nn + ncol;
                #pragma unroll
                for (int r = 0; r < 4; ++r)
                    cp[(size_t)r * Nn] = acc[mf][n][r] + bia;
            }
        }
    }
    #undef STG
    #undef STAGE_T
}

// ---------------------------------------------------------------------------
extern "C" void kernel_launch(void* const* d_in, const int* in_sizes, int n_in,
                              void* d_out, int out_size, void* d_ws, size_t ws_size,
                              hipStream_t stream)
{
    const float* x     = (const float*)d_in[0];
    // d_in[1] = lst_lens (uniform K=20, unused)
    const float* q     = (const float*)d_in[2];
    const float* W_att = (const float*)d_in[3];
    const float* b_att = (const float*)d_in[4];
    const float* W_fc  = (const float*)d_in[5];
    const float* b_fc  = (const float*)d_in[6];

    float* feats  = (float*)d_out;                    // [B, C]
    float* logits = feats + (size_t)BB * CC;          // [B, NCLS]

    float* r_buf  = logits;                           // [B, C] scratch (fallback)
    float* nq_buf = logits + (size_t)BB * CC;         // [B, C] scratch

    // workspace layout (Arb aliases Abuf -- disjoint lifetimes):
    //   Abuf/Arb [BB,KSP] | Bbuf [NPAD,KSP] | Wab [CC,KSP]
    unsigned short* Abuf = (unsigned short*)d_ws;
    unsigned short* Bbuf = Abuf + (size_t)BB * KSP;
    unsigned short* Wab  = Bbuf + (size_t)NPAD * KSP;
    unsigned short* Arb  = Abuf;

    const size_t need_cls = (size_t)(BB + NPAD) * KSP * 2;       // 39.7 MB
    const size_t need_all = need_cls + (size_t)CC * KSP * 2;     // 41.2 MB
    const bool mfma_cls = ws_size >= need_cls;
    const bool mfma_att = ws_size >= need_all;

    // weight conversions (independent)
    if (mfma_cls)
        conv_split_w<<<(NPAD * (CC / 4)) / 256, 256, 0, stream>>>(
            W_fc, Bbuf, NCLS, NPAD);
    if (mfma_att)
        conv_split_w<<<(CC * (CC / 4)) / 256, 256, 0, stream>>>(
            W_att, Wab, CC, CC);

    // pass 1: r = softmax(q . xn)-weighted mean (split output fused)
    if (mfma_att)
        pool_kernel<0, 1><<<BB, 320, 0, stream>>>(x, q, (size_t)0, nullptr, Arb);
    else
        pool_kernel<1, 0><<<BB, 320, 0, stream>>>(x, q, (size_t)0, r_buf, nullptr);

    // new_q = tanh(r @ W_att^T + b_att)
    if (mfma_att)
        gemm_mfma_bt<true><<<dim3(BB / 128, CC / 128), 256, 0, stream>>>(
            Arb, Wab, b_att, nq_buf, CC);
    else
        gemm_bt<64, 64, 16, 4, 4, true><<<dim3(BB / 64, CC / 64), 256, 0, stream>>>(
            r_buf, W_att, b_att, nq_buf, BB, CC, CC);

    // pass 2: feats (f32 to d_out) + split into Abuf (fused)
    if (mfma_cls)
        pool_kernel<1, 1><<<BB, 320, 0, stream>>>(x, nq_buf, (size_t)CC, feats, Abuf);
    else
        pool_kernel<1, 0><<<BB, 320, 0, stream>>>(x, nq_buf, (size_t)CC, feats, nullptr);

    // logits = feats @ W_fc^T + b_fc
    if (mfma_cls)
        gemm_cls<<<dim3(MBLK * NBLK), 512, 0, stream>>>(
            Abuf, Bbuf, b_fc, logits, NCLS);
    else
        gemm_bt<128, 128, 8, 8, 8, false><<<dim3(BB / 128, (NCLS + 127) / 128), 256, 0, stream>>>(
            feats, W_fc, b_fc, logits, BB, NCLS, CC);
}